// Round 8
// baseline (199.273 us; speedup 1.0000x reference)
//
#include <hip/hip_runtime.h>
#include <math.h>

#define D_IN  512
#define D_HID 64
#define D_OUT 40

typedef __attribute__((ext_vector_type(8))) short bf16x8;
typedef __attribute__((ext_vector_type(4))) float f32x4;

static __device__ __forceinline__ unsigned short f2bf(float f) {
    unsigned u = __float_as_uint(f);
    return (unsigned short)((u + 0x7FFF + ((u >> 16) & 1)) >> 16);  // RNE
}
static __device__ __forceinline__ float bf2f(unsigned short h) {
    return __uint_as_float(((unsigned)h) << 16);
}

// ===========================================================================
__global__ __launch_bounds__(256)
void zero_counts(int* __restrict__ counts, int N) {
    const int i = blockIdx.x * blockDim.x + threadIdx.x;
    if (i < N) counts[i] = 0;
}

// ===========================================================================
// CSR build, XCD-local: blocks with blockIdx%8==s own dst-slice s, so count
// and CSR-record cache lines are only ever dirtied by ONE XCD's L2.
// ===========================================================================
__global__ __launch_bounds__(256)
void hist_xcd(const int* __restrict__ dst, int* __restrict__ counts, int E, int N) {
    const int slice = (N + 7) >> 3;
    const int lo = (blockIdx.x & 7) * slice;
    const int hi = min(N, lo + slice);
    const int nChunk = gridDim.x >> 3;
    const int per = (E + nChunk - 1) / nChunk;
    const int beg = (blockIdx.x >> 3) * per;
    const int end = min(E, beg + per);
    for (int e = beg + threadIdx.x; e < end; e += blockDim.x) {
        const int d = dst[e];
        if (d >= lo && d < hi) atomicAdd(&counts[d], 1);
    }
}

__global__ __launch_bounds__(256)
void scatter_xcd(const int* __restrict__ src, const int* __restrict__ dstA,
                 const float* __restrict__ wm, int* __restrict__ cursor,
                 int2* __restrict__ edges, int E, int N) {
    const int slice = (N + 7) >> 3;
    const int lo = (blockIdx.x & 7) * slice;
    const int hi = min(N, lo + slice);
    const int nChunk = gridDim.x >> 3;
    const int per = (E + nChunk - 1) / nChunk;
    const int beg = (blockIdx.x >> 3) * per;
    const int end = min(E, beg + per);
    for (int e = beg + threadIdx.x; e < end; e += blockDim.x) {
        const int d = dstA[e];
        if (d >= lo && d < hi) {
            const int pos = atomicAdd(&cursor[d], 1);
            edges[pos] = make_int2(src[e], __float_as_int(wm[e]));
        }
    }
}

// inclusive scan within 256-element blocks; row_start[i]=incl, blockSums[b]=total
__global__ __launch_bounds__(256)
void scan1_kernel(const int* __restrict__ counts, int* __restrict__ row_start,
                  int* __restrict__ blockSums, int N) {
    __shared__ int s[256];
    const int t = threadIdx.x;
    const int i = blockIdx.x * 256 + t;
    const int c = (i < N) ? counts[i] : 0;
    s[t] = c;
    __syncthreads();
#pragma unroll
    for (int off = 1; off < 256; off <<= 1) {
        const int v = s[t] + ((t >= off) ? s[t - off] : 0);
        __syncthreads();
        s[t] = v;
        __syncthreads();
    }
    if (i < N) row_start[i] = s[t];
    if (t == 255) blockSums[blockIdx.x] = s[255];
}

// merged scan2+scan3: every block re-scans the (<=256) blockSums in LDS,
// takes its own exclusive base, finalizes row_start + cursor.
__global__ __launch_bounds__(256)
void scan23_kernel(const int* __restrict__ counts, int* __restrict__ row_start,
                   const int* __restrict__ blockSums, int* __restrict__ cursor,
                   int N, int NB) {
    __shared__ int s[256];
    const int t = threadIdx.x;
    s[t] = (t < NB) ? blockSums[t] : 0;
    __syncthreads();
#pragma unroll
    for (int off = 1; off < 256; off <<= 1) {
        const int v = s[t] + ((t >= off) ? s[t - off] : 0);
        __syncthreads();
        s[t] = v;
        __syncthreads();
    }
    const int base = (blockIdx.x == 0) ? 0 : s[blockIdx.x - 1];
    const int i = blockIdx.x * 256 + t;
    if (i < N) {
        const int c = counts[i];
        const int start = row_start[i] - c + base;
        row_start[i] = start;
        cursor[i] = start;
        if (i == N - 1) row_start[N] = start + c;
    }
}

// ===========================================================================
// prep: W1[512][64] fp32 -> w1T[64][512] bf16 (B-operand, contiguous k)
// ===========================================================================
__global__ void prep_w1(const float* __restrict__ W1, unsigned short* __restrict__ w1T) {
    const int i = blockIdx.x * blockDim.x + threadIdx.x;  // i = k*64 + col
    if (i < D_IN * D_HID) {
        const int k = i >> 6, col = i & 63;
        w1T[col * D_IN + k] = f2bf(W1[i]);
    }
}

// ===========================================================================
// GEMM1 (MFMA bf16): h1[N,64](bf16) = x[N,512] @ W1 + b1
// ===========================================================================
__global__ __launch_bounds__(256)
void gemm1_mfma(const float* __restrict__ x, const unsigned short* __restrict__ w1T,
                const float* __restrict__ b1, unsigned short* __restrict__ h1, int N) {
    __shared__ unsigned char lds[16384];  // xs @0, ws @8192
    const int t = threadIdx.x;
    const int lane = t & 63;
    const int wv = t >> 6;
    const int nodeBase = blockIdx.x * 64;

    f32x4 acc[4];
#pragma unroll
    for (int cg = 0; cg < 4; ++cg) acc[cg] = (f32x4){0.f, 0.f, 0.f, 0.f};

    for (int k0 = 0; k0 < D_IN; k0 += 64) {
#pragma unroll
        for (int hh = 0; hh < 2; ++hh) {
            const int g = t + hh * 256;          // 0..511
            const int row = g >> 3, slot = g & 7;
            int gn = nodeBase + row; if (gn >= N) gn = N - 1;
            const float* sp = x + (size_t)gn * D_IN + k0 + slot * 8;
            const float4 a = *reinterpret_cast<const float4*>(sp);
            const float4 b = *reinterpret_cast<const float4*>(sp + 4);
            uint4 p;
            p.x = (unsigned)f2bf(a.x) | ((unsigned)f2bf(a.y) << 16);
            p.y = (unsigned)f2bf(a.z) | ((unsigned)f2bf(a.w) << 16);
            p.z = (unsigned)f2bf(b.x) | ((unsigned)f2bf(b.y) << 16);
            p.w = (unsigned)f2bf(b.z) | ((unsigned)f2bf(b.w) << 16);
            *reinterpret_cast<uint4*>(lds + row * 128 + ((slot << 4) ^ ((row & 7) << 4))) = p;
        }
#pragma unroll
        for (int hh = 0; hh < 2; ++hh) {
            const int g = t + hh * 256;
            const int col = g >> 3, slot = g & 7;
            const uint4 p = *reinterpret_cast<const uint4*>(w1T + (size_t)col * D_IN + k0 + slot * 8);
            *reinterpret_cast<uint4*>(lds + 8192 + col * 128 + ((slot << 4) ^ ((col & 7) << 4))) = p;
        }
        __syncthreads();

        const int fr = lane & 15;
        const int fc = lane >> 4;
#pragma unroll
        for (int s = 0; s < 2; ++s) {
            const int slot = s * 4 + fc;
            const int arow = wv * 16 + fr;
            const bf16x8 afrag = *reinterpret_cast<const bf16x8*>(
                lds + arow * 128 + ((slot << 4) ^ ((arow & 7) << 4)));
#pragma unroll
            for (int cg = 0; cg < 4; ++cg) {
                const int brow = cg * 16 + fr;
                const bf16x8 bfrag = *reinterpret_cast<const bf16x8*>(
                    lds + 8192 + brow * 128 + ((slot << 4) ^ ((brow & 7) << 4)));
                acc[cg] = __builtin_amdgcn_mfma_f32_16x16x32_bf16(afrag, bfrag, acc[cg], 0, 0, 0);
            }
        }
        __syncthreads();
    }

    const int fr = lane & 15;
    const int rq = lane >> 4;
#pragma unroll
    for (int cg = 0; cg < 4; ++cg) {
        const int col = cg * 16 + fr;
        const float bb = b1[col];
#pragma unroll
        for (int r = 0; r < 4; ++r) {
            const int node = nodeBase + wv * 16 + rq * 4 + r;
            if (node < N)
                h1[(size_t)node * D_HID + col] = f2bf(acc[cg][r] + bb);
        }
    }
}

// ===========================================================================
// CSR aggregation, 64 ch: wave/node, lane=channel. Shfl-broadcast edge
// records; 4 independent gathers in flight. Fused relu + bf16 store.
// ===========================================================================
__global__ __launch_bounds__(256)
void agg_csr_hid(const unsigned short* __restrict__ h, const int2* __restrict__ edges,
                 const int* __restrict__ row_start, unsigned short* __restrict__ agg1, int N) {
    const int lane = threadIdx.x & 63;
    const int n = (blockIdx.x * blockDim.x + threadIdx.x) >> 6;
    if (n >= N) return;
    const int beg = row_start[n];
    const int end = row_start[n + 1];
    float acc = 0.f;
    for (int base = beg; base < end; base += 64) {
        const int cnt = min(64, end - base);
        int2 er = make_int2(0, 0);
        if (base + lane < end) er = edges[base + lane];
        int j = 0;
        for (; j + 4 <= cnt; j += 4) {
            const int   s0 = __shfl(er.x, j + 0), s1 = __shfl(er.x, j + 1);
            const int   s2 = __shfl(er.x, j + 2), s3 = __shfl(er.x, j + 3);
            const float w0 = __int_as_float(__shfl(er.y, j + 0));
            const float w1 = __int_as_float(__shfl(er.y, j + 1));
            const float w2 = __int_as_float(__shfl(er.y, j + 2));
            const float w3 = __int_as_float(__shfl(er.y, j + 3));
            const float v0 = bf2f(h[(size_t)s0 * D_HID + lane]);
            const float v1 = bf2f(h[(size_t)s1 * D_HID + lane]);
            const float v2 = bf2f(h[(size_t)s2 * D_HID + lane]);
            const float v3 = bf2f(h[(size_t)s3 * D_HID + lane]);
            acc += w0 * v0; acc += w1 * v1; acc += w2 * v2; acc += w3 * v3;
        }
        for (; j < cnt; ++j) {
            const int   s0 = __shfl(er.x, j);
            const float w0 = __int_as_float(__shfl(er.y, j));
            acc += w0 * bf2f(h[(size_t)s0 * D_HID + lane]);
        }
    }
    agg1[(size_t)n * D_HID + lane] = f2bf(fmaxf(acc, 0.f));  // fused relu
}

// ===========================================================================
// Layer 2, fully fused (algebraic reassociation):
//   out[n] = lsm( (Σ_e w_e·relu(agg1)[src_e]) @ W2  +  (Σ_e w_e)·b2 )
// Wave/node 64-ch gather (all lanes active), per-wave LDS transpose,
// 64->40 matvec from LDS-resident W2, log_softmax — one kernel, no h2.
// ===========================================================================
__global__ __launch_bounds__(256)
void agg2_lsm(const unsigned short* __restrict__ hrelu, const int2* __restrict__ edges,
              const int* __restrict__ row_start, const float* __restrict__ W2,
              const float* __restrict__ b2, float* __restrict__ out, int N) {
    __shared__ float w2s[D_HID * D_OUT];   // 10.24 KB
    __shared__ float b2s[D_OUT];
    __shared__ float tb[4][D_HID];         // per-wave t vector
    for (int i = threadIdx.x; i < D_HID * D_OUT; i += 256) w2s[i] = W2[i];
    if (threadIdx.x < D_OUT) b2s[threadIdx.x] = b2[threadIdx.x];
    __syncthreads();

    const int lane = threadIdx.x & 63;
    const int wid  = threadIdx.x >> 6;
    const int n = (blockIdx.x * blockDim.x + threadIdx.x) >> 6;
    if (n >= N) return;

    const int beg = row_start[n];
    const int end = row_start[n + 1];
    float acc = 0.f;   // t[lane]
    float accw = 0.f;  // Σ w_e (identical in every lane)
    for (int base = beg; base < end; base += 64) {
        const int cnt = min(64, end - base);
        int2 er = make_int2(0, 0);
        if (base + lane < end) er = edges[base + lane];
        int j = 0;
        for (; j + 4 <= cnt; j += 4) {
            const int   s0 = __shfl(er.x, j + 0), s1 = __shfl(er.x, j + 1);
            const int   s2 = __shfl(er.x, j + 2), s3 = __shfl(er.x, j + 3);
            const float w0 = __int_as_float(__shfl(er.y, j + 0));
            const float w1 = __int_as_float(__shfl(er.y, j + 1));
            const float w2 = __int_as_float(__shfl(er.y, j + 2));
            const float w3 = __int_as_float(__shfl(er.y, j + 3));
            const float v0 = bf2f(hrelu[(size_t)s0 * D_HID + lane]);
            const float v1 = bf2f(hrelu[(size_t)s1 * D_HID + lane]);
            const float v2 = bf2f(hrelu[(size_t)s2 * D_HID + lane]);
            const float v3 = bf2f(hrelu[(size_t)s3 * D_HID + lane]);
            acc += w0 * v0; acc += w1 * v1; acc += w2 * v2; acc += w3 * v3;
            accw += w0 + w1 + w2 + w3;
        }
        for (; j < cnt; ++j) {
            const int   s0 = __shfl(er.x, j);
            const float w0 = __int_as_float(__shfl(er.y, j));
            acc += w0 * bf2f(hrelu[(size_t)s0 * D_HID + lane]);
            accw += w0;
        }
    }

    // per-wave transpose: lane k holds t[k]; matvec needs t broadcast
    tb[wid][lane] = acc;   // wave-private LDS; compiler orders via lgkmcnt
    float v = -INFINITY;
    if (lane < D_OUT) {
        float a = accw * b2s[lane];
#pragma unroll
        for (int k = 0; k < D_HID; ++k)
            a = fmaf(tb[wid][k], w2s[k * D_OUT + lane], a);
        v = a;
    }

    // log_softmax over 40 classes
    float m = v;
#pragma unroll
    for (int o = 32; o > 0; o >>= 1) m = fmaxf(m, __shfl_xor(m, o, 64));
    float s = (lane < D_OUT) ? __expf(v - m) : 0.f;
#pragma unroll
    for (int o = 32; o > 0; o >>= 1) s += __shfl_xor(s, o, 64);
    if (lane < D_OUT) out[(size_t)n * D_OUT + lane] = v - m - __logf(s);
}

// ===========================================================================
extern "C" void kernel_launch(void* const* d_in, const int* in_sizes, int n_in,
                              void* d_out, int out_size, void* d_ws, size_t ws_size,
                              hipStream_t stream) {
    const float* x   = (const float*)d_in[0];
    const int*   ei  = (const int*)d_in[1];
    const float* wm  = (const float*)d_in[2];
    const float* W1  = (const float*)d_in[3];
    const float* b1  = (const float*)d_in[4];
    const float* W2  = (const float*)d_in[5];
    const float* b2  = (const float*)d_in[6];

    const int N = in_sizes[0] / D_IN;   // 50000
    const int E = in_sizes[2];          // 800000
    const int* srcIdx = ei;
    const int* dstIdx = ei + E;

    // workspace layout (16B-aligned blocks first)
    unsigned short* w1T    = (unsigned short*)d_ws;                  // 64 KiB
    unsigned short* h1bf   = w1T + (size_t)D_HID * D_IN;             // N*64 bf16
    unsigned short* agg1bf = h1bf + (size_t)N * D_HID;               // N*64 bf16 (relu'd)
    int2*  edges           = (int2*)(agg1bf + (size_t)N * D_HID);    // E int2
    int*   row_start       = (int*)(edges + E);                      // N+1
    int*   cursor          = row_start + (N + 1);                    // N
    int*   counts          = cursor + N;                             // N
    int*   blockSums       = counts + N;                             // <=256
    float* out             = (float*)d_out;

    const int NB = (N + 255) / 256;  // 196

    // ---- CSR build (XCD-local hist + scatter)
    zero_counts<<<NB, 256, 0, stream>>>(counts, N);
    hist_xcd<<<2048, 256, 0, stream>>>(dstIdx, counts, E, N);
    scan1_kernel<<<NB, 256, 0, stream>>>(counts, row_start, blockSums, N);
    scan23_kernel<<<NB, 256, 0, stream>>>(counts, row_start, blockSums, cursor, N, NB);
    scatter_xcd<<<2048, 256, 0, stream>>>(srcIdx, dstIdx, wm, cursor, edges, E, N);

    // ---- network (gemm2 folded into agg2_lsm via linearity of aggregation)
    prep_w1<<<(D_IN * D_HID + 255) / 256, 256, 0, stream>>>(W1, w1T);
    gemm1_mfma<<<(N + 63) / 64, 256, 0, stream>>>(x, w1T, b1, h1bf, N);
    agg_csr_hid<<<(N * 64 + 255) / 256, 256, 0, stream>>>(h1bf, edges, row_start, agg1bf, N);
    agg2_lsm<<<(N * 64 + 255) / 256, 256, 0, stream>>>(agg1bf, edges, row_start, W2, b2, out, N);
}